// Round 11
// baseline (238.055 us; speedup 1.0000x reference)
//
#include <hip/hip_runtime.h>
#include <cmath>

#define NN 4096
#define KK 32
#define DD 256
#define HH 128
#define G3 384   // 3*H
#define CH 16    // xw0 chunk steps staged in LDS
#define RH 136   // padded f16 stride of one h-half in the h1 ring

typedef __attribute__((ext_vector_type(8))) _Float16 h8;
typedef __attribute__((ext_vector_type(4))) float f32x4;

// Workgroup barrier that drains ONLY LDS (lgkmcnt), leaving global loads in
// flight across the barrier. __syncthreads() would emit s_waitcnt vmcnt(0)
// and expose the full HBM latency of any in-flight prefetch at the barrier.
__device__ __forceinline__ void bar_lds() {
  asm volatile("s_waitcnt lgkmcnt(0)" ::: "memory");
  __builtin_amdgcn_s_barrier();
}

// ---------------------------------------------------------------------------
// Kernel 1: PREP — all pre-recurrence work in one launch, 337 blocks x 256.
//   blocks 0..71  : pack {W_hh0, W_ih1, W_hh1} into f16 B-fragments
//   blocks 72..79 : per-cluster order lists + len (1 cluster per wave)
//   block  80     : weight-norm scale g/||v||
//   blocks 81..272: xw0 gemm, UNSORTED, register-prefetch pipelined
//   blocks 273..336: sdot[i] = sent_i . v[0:256]
// ---------------------------------------------------------------------------
__global__ __launch_bounds__(256) void prep_k(
    const int* __restrict__ labels, const float* __restrict__ lin_v,
    const float* __restrict__ lin_g,
    const float* __restrict__ Whh0, const float* __restrict__ Wih1,
    const float* __restrict__ Whh1,
    const float* __restrict__ sent, const float* __restrict__ W_ih0,
    const float* __restrict__ b_ih0,
    int* __restrict__ order, int* __restrict__ len, float* __restrict__ scale,
    _Float16* __restrict__ P, float* __restrict__ xw,
    float* __restrict__ sdot) {
  const int blk = blockIdx.x;
  const int t = threadIdx.x;
  if (blk < 72) {                       // ---- pack ----
    const int gid = blk * 256 + t;      // < 18432
    const int lane = gid & 63;
    const int kt = (gid >> 6) & 3;
    const int nt = (gid >> 8) % 24;
    const int mat = (gid >> 8) / 24;
    const float* W = (mat == 0) ? Whh0 : (mat == 1 ? Wih1 : Whh1);
    const int n = nt * 16 + (lane & 15);
    const int kbase = kt * 32 + (lane >> 4) * 8;
    _Float16* dst = P + (size_t)gid * 8;
#pragma unroll
    for (int j = 0; j < 8; ++j) dst[j] = (_Float16)W[(size_t)n * HH + kbase + j];
    return;
  }
  if (blk < 80) {                       // ---- order/len: 1 cluster/wave ----
    const int wv = t >> 6, lane = t & 63;
    const int c = (blk - 72) * 4 + wv;
    int count = 0;
    for (int base = 0; base < NN; base += 64) {
      const int i = base + lane;
      const bool f = (labels[i] == c);
      const unsigned long long m = __ballot(f);
      if (f) order[c * NN + count + __popcll(m & ((1ull << lane) - 1ull))] = i;
      count += __popcll(m);
    }
    if (lane == 0) len[c] = count;
    return;
  }
  if (blk == 80) {                      // ---- scale ----
    if (t < 64) {
      float s = 0.f;
      for (int j = t; j < G3; j += 64) { const float v = lin_v[j]; s += v * v; }
      for (int off = 32; off; off >>= 1) s += __shfl_down(s, off);
      if (t == 0) scale[0] = lin_g[0] / sqrtf(s);
    }
    return;
  }
  if (blk >= 273) {                     // ---- sdot: sent . v[0:256] ----
    const int b = blk - 273;            // 0..63, 64 rows per block
    const int wv = t >> 6, lane = t & 63;
    const float4 vv = *(const float4*)(lin_v + lane * 4);
    const int r0 = b * 64 + wv * 16;
    for (int rr = 0; rr < 16; ++rr) {
      const int r = r0 + rr;
      const float4 a = *(const float4*)(sent + (size_t)r * DD + lane * 4);
      float d = a.x * vv.x + a.y * vv.y + a.z * vv.z + a.w * vv.w;
      for (int off = 32; off; off >>= 1) d += __shfl_down(d, off);
      if (lane == 0) sdot[r] = d;
    }
    return;
  }
  // ---- gemm: xw[i][g] = b_ih0[g] + sum_d sent[i][d] * W_ih0[g][d] --------
  // Register-prefetch pipelined: next k0's tiles load while current computes;
  // lgkm-only barriers keep those global loads in flight.
  __shared__ float Xs[16][132];
  __shared__ float Ws[16][68];
  const int g = blk - 81;               // 0..191
  const int i0 = (g & 31) * 128;
  const int g0 = (g >> 5) * 64;
  const int it = t & 15;
  const int gt = t >> 4;
  const int u0 = t * 2, u1 = t * 2 + 1;
  const int ra0 = u0 >> 2, ca0 = u0 & 3;
  const int ra1 = u1 >> 2, ca1 = u1 & 3;
  const int rw_ = t >> 2, cw_ = t & 3;
  float acc[8][4] = {};
  float4 x0, x1, w0;
  x0 = *(const float4*)(sent + (size_t)(i0 + ra0) * DD + ca0 * 4);
  x1 = *(const float4*)(sent + (size_t)(i0 + ra1) * DD + ca1 * 4);
  w0 = *(const float4*)(W_ih0 + (size_t)(g0 + rw_) * DD + cw_ * 4);
  for (int k0 = 0; k0 < DD; k0 += 16) {
    Xs[ca0 * 4 + 0][ra0] = x0.x; Xs[ca0 * 4 + 1][ra0] = x0.y;
    Xs[ca0 * 4 + 2][ra0] = x0.z; Xs[ca0 * 4 + 3][ra0] = x0.w;
    Xs[ca1 * 4 + 0][ra1] = x1.x; Xs[ca1 * 4 + 1][ra1] = x1.y;
    Xs[ca1 * 4 + 2][ra1] = x1.z; Xs[ca1 * 4 + 3][ra1] = x1.w;
    Ws[cw_ * 4 + 0][rw_] = w0.x; Ws[cw_ * 4 + 1][rw_] = w0.y;
    Ws[cw_ * 4 + 2][rw_] = w0.z; Ws[cw_ * 4 + 3][rw_] = w0.w;
    bar_lds();
    if (k0 + 16 < DD) {                 // issue next chunk; waits land at the
      const int kn = k0 + 16;           // ds_writes next iteration (covered)
      x0 = *(const float4*)(sent + (size_t)(i0 + ra0) * DD + kn + ca0 * 4);
      x1 = *(const float4*)(sent + (size_t)(i0 + ra1) * DD + kn + ca1 * 4);
      w0 = *(const float4*)(W_ih0 + (size_t)(g0 + rw_) * DD + kn + cw_ * 4);
    }
#pragma unroll
    for (int k = 0; k < 16; ++k) {
      float a[8], b[4];
#pragma unroll
      for (int x = 0; x < 8; ++x) a[x] = Xs[k][it * 8 + x];
#pragma unroll
      for (int y = 0; y < 4; ++y) b[y] = Ws[k][gt * 4 + y];
#pragma unroll
      for (int x = 0; x < 8; ++x)
#pragma unroll
        for (int y = 0; y < 4; ++y)
          acc[x][y] += a[x] * b[y];
    }
    bar_lds();
  }
  const float4 bs = *(const float4*)(b_ih0 + g0 + gt * 4);
#pragma unroll
  for (int x = 0; x < 8; ++x) {
    const int gi = i0 + it * 8 + x;
    float4 o;
    o.x = acc[x][0] + bs.x; o.y = acc[x][1] + bs.y;
    o.z = acc[x][2] + bs.z; o.w = acc[x][3] + bs.w;
    *(float4*)(xw + (size_t)gi * G3 + g0 + gt * 4) = o;
  }
}

// ---------------------------------------------------------------------------
// Kernel 2: FUSED 2-layer GRU — champion structure, xw1 batch cadence
// 4 -> 2 steps (lag 5 -> 3). Same transformation that won R9 (8->4, -4us):
//   - loop runs Lr+3 iterations (2 fewer drain iters on the critical block)
//   - G1 batches every 2nd iter: A rows 0-3 = 2 steps x hi/lo, rows 4-15
//     clamped duplicates; only q==0 stores (steps 0,1 live in q=0's a[0..3])
//   - xw1buf shrinks 12 KB -> 6 KB
// Race-checked: batch at even it2 reads ring (it2-2),(it2-1)&15, G0 writes
// it2&15 (disjoint); buffers alternate (c2>>1)&1 with one barrier between
// G1's write and G2's read for both odd and even Lr.
// ---------------------------------------------------------------------------
__global__ __launch_bounds__(768) void gru_fused_k(
    const float* __restrict__ xw0,          // UNSORTED [NN][384] fp32
    const _Float16* __restrict__ pack,      // [3][24][4][64][8] f16 frags
    const float* __restrict__ b_hh0, const float* __restrict__ b_ih0,
    const float* __restrict__ b_ih1, const float* __restrict__ b_hh1,
    const int* __restrict__ len, const int* __restrict__ order,
    const float* __restrict__ sdot,
    const float* __restrict__ lin_v, const float* __restrict__ scale,
    const float* __restrict__ lin_b, float* __restrict__ out) {
  const int c = blockIdx.x;
  const int t = threadIdx.x;
  const int wv = t >> 6, lane = t & 63;
  const int group = wv >> 2;                // 0:L0-hw  1:xw1-batch  2:L1-hw
  const int v = wv & 3;
  // ---- preload B fragments (loop-invariant) -------------------------------
  h8 B[6][4];
  {
    const _Float16* mp = pack + (size_t)group * (24 * 4 * 64 * 8);
#pragma unroll
    for (int i = 0; i < 6; ++i) {
      const int nt = (i >> 1) * 8 + 2 * v + (i & 1);
#pragma unroll
      for (int kt = 0; kt < 4; ++kt)
        B[i][kt] = *(const h8*)(mp + ((size_t)(nt * 4 + kt) * 64 + lane) * 8);
    }
  }
  const int L = len[c];
  const int Lr = (L > 0) ? L : 1;
  const bool use_bih0 = (L == 0);
  // gather-staging constants: element e -> chunk row u = e/96, float4 f = e%96
  const int u0 = t / 96, f0 = t - u0 * 96;
  const int u1 = (t + 768) / 96, f1 = (t + 768) - u1 * 96;
  const float4* const xsrc = (const float4*)xw0;
  // ---- LDS ----------------------------------------------------------------
  __shared__ __align__(16) float xwbuf[2 * CH * G3];     // 48 KB dbuf chunks
  __shared__ __align__(16) _Float16 ring[16][2 * RH];    // h1 ring, padded
  __shared__ __align__(16) _Float16 hp2[2][2][HH];       // h2 [par][hi/lo]
  __shared__ float xw1buf[2][2][G3];                     // [chunk&1][step][gate]
  __shared__ float ce_s[HH];
  __shared__ float vbuf[HH];                             // lin_v[256:384]
  __shared__ float sc_s[2048];
  __shared__ float sc_red;
  {
    _Float16* rp = &ring[0][0];
    for (int u = t; u < 16 * 2 * RH; u += 768) rp[u] = (_Float16)0.f;
  }
  if (t < HH) {
    hp2[0][0][t] = (_Float16)0.f; hp2[0][1][t] = (_Float16)0.f;
    hp2[1][0][t] = (_Float16)0.f; hp2[1][1][t] = (_Float16)0.f;
  }
  // prologue: stage chunk 0 (gathered via order, clamped)
  if (!use_bih0) {
    float4* dst = (float4*)xwbuf;
    const int r0 = (u0 < L) ? order[c * NN + u0] : 0;
    const int r1 = (u1 < L) ? order[c * NN + u1] : 0;
    dst[t] = xsrc[(size_t)r0 * 96 + f0];
    dst[t + 768] = xsrc[(size_t)r1 * 96 + f1];
  }
  // ---- per-lane gate constants (lanes 0..31: one gate each) ---------------
  const int tg = 32 * v + (lane & 31);      // this lane's gate id
  float bhr = 0.f, bhz = 0.f, bhn = 0.f;
  float bir = 0.f, biz = 0.f, bin = 0.f;
  float h = 0.f;                            // h1 slice (G0) / h2 slice (G2)
  if (lane < 32) {
    if (group == 0) {
      bhr = b_hh0[tg]; bhz = b_hh0[HH + tg]; bhn = b_hh0[2 * HH + tg];
      if (use_bih0) {
        bir = b_ih0[tg]; biz = b_ih0[HH + tg]; bin = b_ih0[2 * HH + tg];
      }
    } else if (group == 2) {
      bhr = b_hh1[tg]; bhz = b_hh1[HH + tg]; bhn = b_hh1[2 * HH + tg];
      bir = b_ih1[tg]; biz = b_ih1[HH + tg]; bin = b_ih1[2 * HH + tg];
    }
  }
  __syncthreads();   // init + chunk-0 staging visible (vmcnt drain wanted once)
  const int q = lane >> 4;
  const int row = lane & 15;
  const int hs = (row == 0 || row == 4) ? 0 : 1;  // rows 0,4 = hi; 1,5 = lo
  const bool hiacc = ((lane >> 4) & 1) != 0;      // lanes 16-31: use odd accs
  float4 pf0 = {0.f, 0.f, 0.f, 0.f}, pf1 = {0.f, 0.f, 0.f, 0.f};
  bool pfv = false;
  for (int it2 = 0; it2 < Lr + 3; ++it2) {
    const int par = it2 & 1;
    const int ph = it2 & (CH - 1);
    // ---- split-stage next xw0 chunk: issue at ph6, write at ph14 ---------
    if (!use_bih0) {
      if (ph == 6) {
        const int s = (it2 & ~(CH - 1)) + CH;       // next chunk start
        if (s < Lr) {
          const int p0 = s + u0;
          const int p1 = s + u1;
          const int r0 = (p0 < L) ? order[c * NN + p0] : 0;
          const int r1 = (p1 < L) ? order[c * NN + p1] : 0;
          pf0 = xsrc[(size_t)r0 * 96 + f0];
          pf1 = xsrc[(size_t)r1 * 96 + f1];
          pfv = true;
        }
      } else if (ph == 14 && pfv) {
        const int s = (it2 & ~(CH - 1)) + CH;
        float4* dst = (float4*)(xwbuf + (((s >> 4) & 1) ? CH * G3 : 0));
        dst[t] = pf0;
        dst[t + 768] = pf1;
        pfv = false;
      }
    }
    if (group == 0) {
      if (it2 < Lr) {
        // hoist gate inputs (LDS latency hides under MFMAs)
        float xr = bir, xz = biz, xn = bin;
        if (!use_bih0 && lane < 32) {
          const float* xrow = xwbuf + ((it2 >> 4) & 1) * (CH * G3)
                                    + (it2 & (CH - 1)) * G3;
          xr = xrow[tg]; xz = xrow[HH + tg]; xn = xrow[2 * HH + tg];
        }
        const _Float16* abse = &ring[(it2 - 1) & 15][hs * RH];
        h8 A[4];
#pragma unroll
        for (int kt = 0; kt < 4; ++kt)
          A[kt] = *(const h8*)(abse + kt * 32 + q * 8);
        f32x4 a0[6];
#pragma unroll
        for (int i = 0; i < 6; ++i) {
          f32x4 a = {0.f, 0.f, 0.f, 0.f};
#pragma unroll
          for (int kt = 0; kt < 4; ++kt)
            a = __builtin_amdgcn_mfma_f32_16x16x32_f16(A[kt], B[i][kt], a, 0, 0, 0);
          a0[i] = a;
        }
        if (lane < 32) {                     // ONE gate per lane (cndmask pick)
          const float hwrA = a0[0][0] + a0[0][1], hwrB = a0[1][0] + a0[1][1];
          const float hwzA = a0[2][0] + a0[2][1], hwzB = a0[3][0] + a0[3][1];
          const float hwnA = a0[4][0] + a0[4][1], hwnB = a0[5][0] + a0[5][1];
          const float hwr = hiacc ? hwrB : hwrA;
          const float hwz = hiacc ? hwzB : hwzA;
          const float hwn = hiacc ? hwnB : hwnA;
          const float r = 1.f / (1.f + __expf(-(xr + bhr + hwr)));
          const float z = 1.f / (1.f + __expf(-(xz + bhz + hwz)));
          float tgt = xn + r * (bhn + hwn);
          tgt = fminf(fmaxf(tgt, -15.f), 15.f);
          const float e = __expf(2.f * tgt);
          const float n = (e - 1.f) / (e + 1.f);
          h = (1.f - z) * n + z * h;
          const _Float16 hi = (_Float16)h;
          _Float16* rs = &ring[it2 & 15][0];
          rs[tg] = hi;  rs[RH + tg] = (_Float16)(h - (float)hi);
        }
      }
    } else if (group == 1) {
      if (it2 >= 2 && (it2 & 1) == 0 && it2 - 2 < Lr) {
        // batched xw1 for steps [it2-2, it2): A rows 0-3 = 2 steps x hi/lo,
        // rows 4-15 clamped duplicates (never reads slot it2&15).
        const int c2 = it2 - 2;
        const int m = lane & 15;
        const int s = (m >> 1) & 1, half = m & 1;
        const _Float16* abse = &ring[(c2 + s) & 15][half * RH];
        h8 A[4];
#pragma unroll
        for (int kt = 0; kt < 4; ++kt)
          A[kt] = *(const h8*)(abse + kt * 32 + q * 8);
        const int cbuf = (c2 >> 1) & 1;
        float* xo0 = &xw1buf[cbuf][0][0];           // step c2
        float* xo1 = &xw1buf[cbuf][1][0];           // step c2+1
#pragma unroll
        for (int i = 0; i < 6; ++i) {
          f32x4 a = {0.f, 0.f, 0.f, 0.f};
#pragma unroll
          for (int kt = 0; kt < 4; ++kt)
            a = __builtin_amdgcn_mfma_f32_16x16x32_f16(A[kt], B[i][kt], a, 0, 0, 0);
          const int nt = (i >> 1) * 8 + 2 * v + (i & 1);
          const int col = nt * 16 + (lane & 15);
          if (q == 0) {                      // rows 4-15 are duplicates
            xo0[col] = a[0] + a[1];
            xo1[col] = a[2] + a[3];
          }
        }
      }
    } else {
      if (it2 >= 3) {                        // L1: j = it2 - 3
        const int j = it2 - 3;
        float xr = 0.f, xz = 0.f, xn = 0.f;
        if (lane < 32) {
          const float* xi = xw1buf[(j >> 1) & 1][j & 1];
          xr = xi[tg] + bir; xz = xi[HH + tg] + biz; xn = xi[2 * HH + tg] + bin;
        }
        const _Float16* hbase = hp2[par][hs];
        h8 A[4];
#pragma unroll
        for (int kt = 0; kt < 4; ++kt)
          A[kt] = *(const h8*)(hbase + kt * 32 + q * 8);
        f32x4 a1[6];
#pragma unroll
        for (int i = 0; i < 6; ++i) {
          f32x4 a = {0.f, 0.f, 0.f, 0.f};
#pragma unroll
          for (int kt = 0; kt < 4; ++kt)
            a = __builtin_amdgcn_mfma_f32_16x16x32_f16(A[kt], B[i][kt], a, 0, 0, 0);
          a1[i] = a;
        }
        if (lane < 32) {
          const float hwrA = a1[0][0] + a1[0][1], hwrB = a1[1][0] + a1[1][1];
          const float hwzA = a1[2][0] + a1[2][1], hwzB = a1[3][0] + a1[3][1];
          const float hwnA = a1[4][0] + a1[4][1], hwnB = a1[5][0] + a1[5][1];
          const float hwr = hiacc ? hwrB : hwrA;
          const float hwz = hiacc ? hwzB : hwzA;
          const float hwn = hiacc ? hwnB : hwnA;
          const float r = 1.f / (1.f + __expf(-(xr + bhr + hwr)));
          const float z = 1.f / (1.f + __expf(-(xz + bhz + hwz)));
          float tgt = xn + r * (bhn + hwn);
          tgt = fminf(fmaxf(tgt, -15.f), 15.f);
          const float e = __expf(2.f * tgt);
          const float n = (e - 1.f) / (e + 1.f);
          h = (1.f - z) * n + z * h;
          const _Float16 hi = (_Float16)h;
          hp2[par ^ 1][0][tg] = hi;
          hp2[par ^ 1][1][tg] = (_Float16)(h - (float)hi);
        }
      }
    }
    bar_lds();   // the ONLY barrier per iter; LDS-only drain
  }
  // ---- scoring tail (cluster c's sentences, sdot precomputed) -------------
  if (L == 0) return;
  if (group == 2 && lane < 32) ce_s[tg] = h;
  if (t < HH) vbuf[t] = lin_v[DD + t];
  __syncthreads();
  if (wv == 0) {   // ce . v[256:384] (per-cluster constant)
    float cd = ce_s[lane] * vbuf[lane] + ce_s[64 + lane] * vbuf[64 + lane];
    for (int off = 32; off; off >>= 1) cd += __shfl_down(cd, off);
    if (lane == 0) sc_red = cd;
  }
  __syncthreads();
  const float cedot = sc_red;
  const float sc = scale[0], lb = lin_b[0];
  const int Lc = (L < 2048) ? L : 2048;
  for (int p = t; p < Lc; p += 768) {
    const int i = order[c * NN + p];
    sc_s[p] = tanhf(sc * (sdot[i] + cedot) + lb);
  }
  __syncthreads();
  if (wv == 0) {   // cluster sum -> 1/sum
    float s = 0.f;
    for (int p = lane; p < Lc; p += 64) s += sc_s[p];
    for (int off = 32; off; off >>= 1) s += __shfl_down(s, off);
    if (lane == 0) sc_red = 1.f / s;
  }
  __syncthreads();
  const float inv = sc_red;
  for (int p = t; p < Lc; p += 768) {
    const int i = order[c * NN + p];
    float ps = __expf(-(float)(i + 1) * 0.0625f);   // 1/4096^(1/3) == 1/16
    ps = fmaxf(0.5f, ps);
    out[i] = 0.5f * (sc_s[p] * inv) + 0.5f * ps;
  }
}

// ---------------------------------------------------------------------------
extern "C" void kernel_launch(void* const* d_in, const int* in_sizes, int n_in,
                              void* d_out, int out_size, void* d_ws, size_t ws_size,
                              hipStream_t stream) {
  const float* sent   = (const float*)d_in[0];
  const int*   labels = (const int*)d_in[1];
  const float* W_ih0  = (const float*)d_in[2];
  const float* W_hh0  = (const float*)d_in[3];
  const float* b_ih0  = (const float*)d_in[4];
  const float* b_hh0  = (const float*)d_in[5];
  const float* W_ih1  = (const float*)d_in[6];
  const float* W_hh1  = (const float*)d_in[7];
  const float* b_ih1  = (const float*)d_in[8];
  const float* b_hh1  = (const float*)d_in[9];
  const float* lin_v  = (const float*)d_in[10];
  const float* lin_g  = (const float*)d_in[11];
  const float* lin_b  = (const float*)d_in[12];
  float* out = (float*)d_out;

  char* ws = (char*)d_ws;
  size_t off = 0;
  auto alloc = [&](size_t bytes) -> void* {
    void* p = ws + off;
    off = (off + bytes + 255) & ~(size_t)255;
    return p;
  };
  int*   order  = (int*)  alloc((size_t)KK * NN * sizeof(int));
  int*   len    = (int*)  alloc(KK * sizeof(int));
  float* scale  = (float*)alloc(sizeof(float));
  _Float16* pack = (_Float16*)alloc((size_t)18432 * 8 * sizeof(_Float16));
  float* xw     = (float*)alloc((size_t)NN * G3 * sizeof(float));
  float* sdot   = (float*)alloc((size_t)NN * sizeof(float));
  (void)ws_size; (void)in_sizes; (void)n_in; (void)out_size;

  prep_k<<<dim3(337), dim3(256), 0, stream>>>(
      labels, lin_v, lin_g, W_hh0, W_ih1, W_hh1,
      sent, W_ih0, b_ih0, order, len, scale, pack, xw, sdot);
  gru_fused_k<<<dim3(KK), dim3(768), 0, stream>>>(
      xw, pack, b_hh0, b_ih0, b_ih1, b_hh1, len, order,
      sdot, lin_v, scale, lin_b, out);
}

// Round 12
// 233.766 us; speedup vs baseline: 1.0183x; 1.0183x over previous
//
#include <hip/hip_runtime.h>
#include <cmath>

#define NN 4096
#define KK 32
#define DD 256
#define HH 128
#define G3 384   // 3*H
#define CH 16    // xw0 chunk steps staged in LDS
#define RH 136   // padded f16 stride of one h-half in the h1 ring

typedef __attribute__((ext_vector_type(8))) _Float16 h8;
typedef __attribute__((ext_vector_type(4))) float f32x4;

// Workgroup barrier that drains ONLY LDS (lgkmcnt), leaving global loads in
// flight across the barrier. __syncthreads() would emit s_waitcnt vmcnt(0)
// and expose the full HBM latency of any in-flight prefetch at the barrier.
__device__ __forceinline__ void bar_lds() {
  asm volatile("s_waitcnt lgkmcnt(0)" ::: "memory");
  __builtin_amdgcn_s_barrier();
}

// ---------------------------------------------------------------------------
// Kernel 1: PREP — all pre-recurrence work in one launch, 337 blocks x 256.
//   blocks 0..71  : pack {W_hh0, W_ih1, W_hh1} into f16 B-fragments
//   blocks 72..79 : per-cluster order lists + len (1 cluster per wave)
//   block  80     : weight-norm scale g/||v||
//   blocks 81..272: xw0 gemm, UNSORTED, register-prefetch pipelined
//   blocks 273..336: sdot[i] = sent_i . v[0:256]
// ---------------------------------------------------------------------------
__global__ __launch_bounds__(256) void prep_k(
    const int* __restrict__ labels, const float* __restrict__ lin_v,
    const float* __restrict__ lin_g,
    const float* __restrict__ Whh0, const float* __restrict__ Wih1,
    const float* __restrict__ Whh1,
    const float* __restrict__ sent, const float* __restrict__ W_ih0,
    const float* __restrict__ b_ih0,
    int* __restrict__ order, int* __restrict__ len, float* __restrict__ scale,
    _Float16* __restrict__ P, float* __restrict__ xw,
    float* __restrict__ sdot) {
  const int blk = blockIdx.x;
  const int t = threadIdx.x;
  if (blk < 72) {                       // ---- pack ----
    const int gid = blk * 256 + t;      // < 18432
    const int lane = gid & 63;
    const int kt = (gid >> 6) & 3;
    const int nt = (gid >> 8) % 24;
    const int mat = (gid >> 8) / 24;
    const float* W = (mat == 0) ? Whh0 : (mat == 1 ? Wih1 : Whh1);
    const int n = nt * 16 + (lane & 15);
    const int kbase = kt * 32 + (lane >> 4) * 8;
    _Float16* dst = P + (size_t)gid * 8;
#pragma unroll
    for (int j = 0; j < 8; ++j) dst[j] = (_Float16)W[(size_t)n * HH + kbase + j];
    return;
  }
  if (blk < 80) {                       // ---- order/len: 1 cluster/wave ----
    const int wv = t >> 6, lane = t & 63;
    const int c = (blk - 72) * 4 + wv;
    int count = 0;
    for (int base = 0; base < NN; base += 64) {
      const int i = base + lane;
      const bool f = (labels[i] == c);
      const unsigned long long m = __ballot(f);
      if (f) order[c * NN + count + __popcll(m & ((1ull << lane) - 1ull))] = i;
      count += __popcll(m);
    }
    if (lane == 0) len[c] = count;
    return;
  }
  if (blk == 80) {                      // ---- scale ----
    if (t < 64) {
      float s = 0.f;
      for (int j = t; j < G3; j += 64) { const float v = lin_v[j]; s += v * v; }
      for (int off = 32; off; off >>= 1) s += __shfl_down(s, off);
      if (t == 0) scale[0] = lin_g[0] / sqrtf(s);
    }
    return;
  }
  if (blk >= 273) {                     // ---- sdot: sent . v[0:256] ----
    const int b = blk - 273;            // 0..63, 64 rows per block
    const int wv = t >> 6, lane = t & 63;
    const float4 vv = *(const float4*)(lin_v + lane * 4);
    const int r0 = b * 64 + wv * 16;
    for (int rr = 0; rr < 16; ++rr) {
      const int r = r0 + rr;
      const float4 a = *(const float4*)(sent + (size_t)r * DD + lane * 4);
      float d = a.x * vv.x + a.y * vv.y + a.z * vv.z + a.w * vv.w;
      for (int off = 32; off; off >>= 1) d += __shfl_down(d, off);
      if (lane == 0) sdot[r] = d;
    }
    return;
  }
  // ---- gemm: xw[i][g] = b_ih0[g] + sum_d sent[i][d] * W_ih0[g][d] --------
  // Register-prefetch pipelined: next k0's tiles load while current computes;
  // lgkm-only barriers keep those global loads in flight.
  __shared__ float Xs[16][132];
  __shared__ float Ws[16][68];
  const int g = blk - 81;               // 0..191
  const int i0 = (g & 31) * 128;
  const int g0 = (g >> 5) * 64;
  const int it = t & 15;
  const int gt = t >> 4;
  const int u0 = t * 2, u1 = t * 2 + 1;
  const int ra0 = u0 >> 2, ca0 = u0 & 3;
  const int ra1 = u1 >> 2, ca1 = u1 & 3;
  const int rw_ = t >> 2, cw_ = t & 3;
  float acc[8][4] = {};
  float4 x0, x1, w0;
  x0 = *(const float4*)(sent + (size_t)(i0 + ra0) * DD + ca0 * 4);
  x1 = *(const float4*)(sent + (size_t)(i0 + ra1) * DD + ca1 * 4);
  w0 = *(const float4*)(W_ih0 + (size_t)(g0 + rw_) * DD + cw_ * 4);
  for (int k0 = 0; k0 < DD; k0 += 16) {
    Xs[ca0 * 4 + 0][ra0] = x0.x; Xs[ca0 * 4 + 1][ra0] = x0.y;
    Xs[ca0 * 4 + 2][ra0] = x0.z; Xs[ca0 * 4 + 3][ra0] = x0.w;
    Xs[ca1 * 4 + 0][ra1] = x1.x; Xs[ca1 * 4 + 1][ra1] = x1.y;
    Xs[ca1 * 4 + 2][ra1] = x1.z; Xs[ca1 * 4 + 3][ra1] = x1.w;
    Ws[cw_ * 4 + 0][rw_] = w0.x; Ws[cw_ * 4 + 1][rw_] = w0.y;
    Ws[cw_ * 4 + 2][rw_] = w0.z; Ws[cw_ * 4 + 3][rw_] = w0.w;
    bar_lds();
    if (k0 + 16 < DD) {                 // issue next chunk; waits land at the
      const int kn = k0 + 16;           // ds_writes next iteration (covered)
      x0 = *(const float4*)(sent + (size_t)(i0 + ra0) * DD + kn + ca0 * 4);
      x1 = *(const float4*)(sent + (size_t)(i0 + ra1) * DD + kn + ca1 * 4);
      w0 = *(const float4*)(W_ih0 + (size_t)(g0 + rw_) * DD + kn + cw_ * 4);
    }
#pragma unroll
    for (int k = 0; k < 16; ++k) {
      float a[8], b[4];
#pragma unroll
      for (int x = 0; x < 8; ++x) a[x] = Xs[k][it * 8 + x];
#pragma unroll
      for (int y = 0; y < 4; ++y) b[y] = Ws[k][gt * 4 + y];
#pragma unroll
      for (int x = 0; x < 8; ++x)
#pragma unroll
        for (int y = 0; y < 4; ++y)
          acc[x][y] += a[x] * b[y];
    }
    bar_lds();
  }
  const float4 bs = *(const float4*)(b_ih0 + g0 + gt * 4);
#pragma unroll
  for (int x = 0; x < 8; ++x) {
    const int gi = i0 + it * 8 + x;
    float4 o;
    o.x = acc[x][0] + bs.x; o.y = acc[x][1] + bs.y;
    o.z = acc[x][2] + bs.z; o.w = acc[x][3] + bs.w;
    *(float4*)(xw + (size_t)gi * G3 + g0 + gt * 4) = o;
  }
}

// ---------------------------------------------------------------------------
// Kernel 2: FUSED 2-layer GRU — FINAL champion (R9 configuration).
// 12 waves: G0 = L0 per-step gates, G1 = batched xw1 every 4 steps (lag 5),
// G2 = L1 per-step gates. lgkm-only barrier per iter; T14 split staging
// (issue ph6 -> ds_write ph14); sdot tail. Measured: gru 137.1 us /
// total 234.3 us.
// Cadence sweep: 8->141.0, 4->137.1 (optimum), 2->141.8 (duplicate-work
// waste overtakes drain savings). Other A/B'd regressions: reg-staging
// off-critical (R3), global_load_lds staging (R4), dual-acc+setprio (R5),
// 8-wave merge (R7). Floor: 165-step serial recurrence, ~1935 cyc/step of
// {LDS hand-off + dependent MFMA chain + serial gate chain + barrier}.
// ---------------------------------------------------------------------------
__global__ __launch_bounds__(768) void gru_fused_k(
    const float* __restrict__ xw0,          // UNSORTED [NN][384] fp32
    const _Float16* __restrict__ pack,      // [3][24][4][64][8] f16 frags
    const float* __restrict__ b_hh0, const float* __restrict__ b_ih0,
    const float* __restrict__ b_ih1, const float* __restrict__ b_hh1,
    const int* __restrict__ len, const int* __restrict__ order,
    const float* __restrict__ sdot,
    const float* __restrict__ lin_v, const float* __restrict__ scale,
    const float* __restrict__ lin_b, float* __restrict__ out) {
  const int c = blockIdx.x;
  const int t = threadIdx.x;
  const int wv = t >> 6, lane = t & 63;
  const int group = wv >> 2;                // 0:L0-hw  1:xw1-batch  2:L1-hw
  const int v = wv & 3;
  // ---- preload B fragments (loop-invariant) -------------------------------
  h8 B[6][4];
  {
    const _Float16* mp = pack + (size_t)group * (24 * 4 * 64 * 8);
#pragma unroll
    for (int i = 0; i < 6; ++i) {
      const int nt = (i >> 1) * 8 + 2 * v + (i & 1);
#pragma unroll
      for (int kt = 0; kt < 4; ++kt)
        B[i][kt] = *(const h8*)(mp + ((size_t)(nt * 4 + kt) * 64 + lane) * 8);
    }
  }
  const int L = len[c];
  const int Lr = (L > 0) ? L : 1;
  const bool use_bih0 = (L == 0);
  // gather-staging constants: element e -> chunk row u = e/96, float4 f = e%96
  const int u0 = t / 96, f0 = t - u0 * 96;
  const int u1 = (t + 768) / 96, f1 = (t + 768) - u1 * 96;
  const float4* const xsrc = (const float4*)xw0;
  // ---- LDS ----------------------------------------------------------------
  __shared__ __align__(16) float xwbuf[2 * CH * G3];     // 48 KB dbuf chunks
  __shared__ __align__(16) _Float16 ring[16][2 * RH];    // h1 ring, padded
  __shared__ __align__(16) _Float16 hp2[2][2][HH];       // h2 [par][hi/lo]
  __shared__ float xw1buf[2][4][G3];                     // [chunk&1][step][gate]
  __shared__ float ce_s[HH];
  __shared__ float vbuf[HH];                             // lin_v[256:384]
  __shared__ float sc_s[2048];
  __shared__ float sc_red;
  {
    _Float16* rp = &ring[0][0];
    for (int u = t; u < 16 * 2 * RH; u += 768) rp[u] = (_Float16)0.f;
  }
  if (t < HH) {
    hp2[0][0][t] = (_Float16)0.f; hp2[0][1][t] = (_Float16)0.f;
    hp2[1][0][t] = (_Float16)0.f; hp2[1][1][t] = (_Float16)0.f;
  }
  // prologue: stage chunk 0 (gathered via order, clamped)
  if (!use_bih0) {
    float4* dst = (float4*)xwbuf;
    const int r0 = (u0 < L) ? order[c * NN + u0] : 0;
    const int r1 = (u1 < L) ? order[c * NN + u1] : 0;
    dst[t] = xsrc[(size_t)r0 * 96 + f0];
    dst[t + 768] = xsrc[(size_t)r1 * 96 + f1];
  }
  // ---- per-lane gate constants (lanes 0..31: one gate each) ---------------
  const int tg = 32 * v + (lane & 31);      // this lane's gate id
  float bhr = 0.f, bhz = 0.f, bhn = 0.f;
  float bir = 0.f, biz = 0.f, bin = 0.f;
  float h = 0.f;                            // h1 slice (G0) / h2 slice (G2)
  if (lane < 32) {
    if (group == 0) {
      bhr = b_hh0[tg]; bhz = b_hh0[HH + tg]; bhn = b_hh0[2 * HH + tg];
      if (use_bih0) {
        bir = b_ih0[tg]; biz = b_ih0[HH + tg]; bin = b_ih0[2 * HH + tg];
      }
    } else if (group == 2) {
      bhr = b_hh1[tg]; bhz = b_hh1[HH + tg]; bhn = b_hh1[2 * HH + tg];
      bir = b_ih1[tg]; biz = b_ih1[HH + tg]; bin = b_ih1[2 * HH + tg];
    }
  }
  __syncthreads();   // init + chunk-0 staging visible (vmcnt drain wanted once)
  const int q = lane >> 4;
  const int row = lane & 15;
  const int hs = (row == 0 || row == 4) ? 0 : 1;  // rows 0,4 = hi; 1,5 = lo
  const bool hiacc = ((lane >> 4) & 1) != 0;      // lanes 16-31: use odd accs
  float4 pf0 = {0.f, 0.f, 0.f, 0.f}, pf1 = {0.f, 0.f, 0.f, 0.f};
  bool pfv = false;
  for (int it2 = 0; it2 < Lr + 5; ++it2) {
    const int par = it2 & 1;
    const int ph = it2 & (CH - 1);
    // ---- split-stage next xw0 chunk: issue at ph6, write at ph14 ---------
    if (!use_bih0) {
      if (ph == 6) {
        const int s = (it2 & ~(CH - 1)) + CH;       // next chunk start
        if (s < Lr) {
          const int p0 = s + u0;
          const int p1 = s + u1;
          const int r0 = (p0 < L) ? order[c * NN + p0] : 0;
          const int r1 = (p1 < L) ? order[c * NN + p1] : 0;
          pf0 = xsrc[(size_t)r0 * 96 + f0];
          pf1 = xsrc[(size_t)r1 * 96 + f1];
          pfv = true;
        }
      } else if (ph == 14 && pfv) {
        const int s = (it2 & ~(CH - 1)) + CH;
        float4* dst = (float4*)(xwbuf + (((s >> 4) & 1) ? CH * G3 : 0));
        dst[t] = pf0;
        dst[t + 768] = pf1;
        pfv = false;
      }
    }
    if (group == 0) {
      if (it2 < Lr) {
        // hoist gate inputs (LDS latency hides under MFMAs)
        float xr = bir, xz = biz, xn = bin;
        if (!use_bih0 && lane < 32) {
          const float* xrow = xwbuf + ((it2 >> 4) & 1) * (CH * G3)
                                    + (it2 & (CH - 1)) * G3;
          xr = xrow[tg]; xz = xrow[HH + tg]; xn = xrow[2 * HH + tg];
        }
        const _Float16* abse = &ring[(it2 - 1) & 15][hs * RH];
        h8 A[4];
#pragma unroll
        for (int kt = 0; kt < 4; ++kt)
          A[kt] = *(const h8*)(abse + kt * 32 + q * 8);
        f32x4 a0[6];
#pragma unroll
        for (int i = 0; i < 6; ++i) {
          f32x4 a = {0.f, 0.f, 0.f, 0.f};
#pragma unroll
          for (int kt = 0; kt < 4; ++kt)
            a = __builtin_amdgcn_mfma_f32_16x16x32_f16(A[kt], B[i][kt], a, 0, 0, 0);
          a0[i] = a;
        }
        if (lane < 32) {                     // ONE gate per lane (cndmask pick)
          const float hwrA = a0[0][0] + a0[0][1], hwrB = a0[1][0] + a0[1][1];
          const float hwzA = a0[2][0] + a0[2][1], hwzB = a0[3][0] + a0[3][1];
          const float hwnA = a0[4][0] + a0[4][1], hwnB = a0[5][0] + a0[5][1];
          const float hwr = hiacc ? hwrB : hwrA;
          const float hwz = hiacc ? hwzB : hwzA;
          const float hwn = hiacc ? hwnB : hwnA;
          const float r = 1.f / (1.f + __expf(-(xr + bhr + hwr)));
          const float z = 1.f / (1.f + __expf(-(xz + bhz + hwz)));
          float tgt = xn + r * (bhn + hwn);
          tgt = fminf(fmaxf(tgt, -15.f), 15.f);
          const float e = __expf(2.f * tgt);
          const float n = (e - 1.f) / (e + 1.f);
          h = (1.f - z) * n + z * h;
          const _Float16 hi = (_Float16)h;
          _Float16* rs = &ring[it2 & 15][0];
          rs[tg] = hi;  rs[RH + tg] = (_Float16)(h - (float)hi);
        }
      }
    } else if (group == 1) {
      if (it2 >= 4 && (it2 & 3) == 0 && it2 - 4 < Lr) {
        // batched xw1 for steps [it2-4, it2): A rows = 4 steps x hi/lo,
        // clamped-duplicated into rows 8-15 (never reads slot it2&15).
        const int c4 = it2 - 4;
        const int m = lane & 15;
        const int s = (m >> 1) & 3, half = m & 1;
        const _Float16* abse = &ring[(c4 + s) & 15][half * RH];
        h8 A[4];
#pragma unroll
        for (int kt = 0; kt < 4; ++kt)
          A[kt] = *(const h8*)(abse + kt * 32 + q * 8);
        const int cbuf = (c4 >> 2) & 1;
        const int qs = (q < 2) ? q : 0;             // pointer-safe clamp
        float* xo0 = &xw1buf[cbuf][2 * qs][0];      // step 2q  (rows 4q,4q+1)
        float* xo1 = &xw1buf[cbuf][2 * qs + 1][0];  // step 2q+1(rows 4q+2,4q+3)
#pragma unroll
        for (int i = 0; i < 6; ++i) {
          f32x4 a = {0.f, 0.f, 0.f, 0.f};
#pragma unroll
          for (int kt = 0; kt < 4; ++kt)
            a = __builtin_amdgcn_mfma_f32_16x16x32_f16(A[kt], B[i][kt], a, 0, 0, 0);
          const int nt = (i >> 1) * 8 + 2 * v + (i & 1);
          const int col = nt * 16 + (lane & 15);
          if (q < 2) {                       // rows 8-15 are duplicates
            xo0[col] = a[0] + a[1];
            xo1[col] = a[2] + a[3];
          }
        }
      }
    } else {
      if (it2 >= 5) {                        // L1: j = it2 - 5
        const int j = it2 - 5;
        float xr = 0.f, xz = 0.f, xn = 0.f;
        if (lane < 32) {
          const float* xi = xw1buf[(j >> 2) & 1][j & 3];
          xr = xi[tg] + bir; xz = xi[HH + tg] + biz; xn = xi[2 * HH + tg] + bin;
        }
        const _Float16* hbase = hp2[par][hs];
        h8 A[4];
#pragma unroll
        for (int kt = 0; kt < 4; ++kt)
          A[kt] = *(const h8*)(hbase + kt * 32 + q * 8);
        f32x4 a1[6];
#pragma unroll
        for (int i = 0; i < 6; ++i) {
          f32x4 a = {0.f, 0.f, 0.f, 0.f};
#pragma unroll
          for (int kt = 0; kt < 4; ++kt)
            a = __builtin_amdgcn_mfma_f32_16x16x32_f16(A[kt], B[i][kt], a, 0, 0, 0);
          a1[i] = a;
        }
        if (lane < 32) {
          const float hwrA = a1[0][0] + a1[0][1], hwrB = a1[1][0] + a1[1][1];
          const float hwzA = a1[2][0] + a1[2][1], hwzB = a1[3][0] + a1[3][1];
          const float hwnA = a1[4][0] + a1[4][1], hwnB = a1[5][0] + a1[5][1];
          const float hwr = hiacc ? hwrB : hwrA;
          const float hwz = hiacc ? hwzB : hwzA;
          const float hwn = hiacc ? hwnB : hwnA;
          const float r = 1.f / (1.f + __expf(-(xr + bhr + hwr)));
          const float z = 1.f / (1.f + __expf(-(xz + bhz + hwz)));
          float tgt = xn + r * (bhn + hwn);
          tgt = fminf(fmaxf(tgt, -15.f), 15.f);
          const float e = __expf(2.f * tgt);
          const float n = (e - 1.f) / (e + 1.f);
          h = (1.f - z) * n + z * h;
          const _Float16 hi = (_Float16)h;
          hp2[par ^ 1][0][tg] = hi;
          hp2[par ^ 1][1][tg] = (_Float16)(h - (float)hi);
        }
      }
    }
    bar_lds();   // the ONLY barrier per iter; LDS-only drain
  }
  // ---- scoring tail (cluster c's sentences, sdot precomputed) -------------
  if (L == 0) return;
  if (group == 2 && lane < 32) ce_s[tg] = h;
  if (t < HH) vbuf[t] = lin_v[DD + t];
  __syncthreads();
  if (wv == 0) {   // ce . v[256:384] (per-cluster constant)
    float cd = ce_s[lane] * vbuf[lane] + ce_s[64 + lane] * vbuf[64 + lane];
    for (int off = 32; off; off >>= 1) cd += __shfl_down(cd, off);
    if (lane == 0) sc_red = cd;
  }
  __syncthreads();
  const float cedot = sc_red;
  const float sc = scale[0], lb = lin_b[0];
  const int Lc = (L < 2048) ? L : 2048;
  for (int p = t; p < Lc; p += 768) {
    const int i = order[c * NN + p];
    sc_s[p] = tanhf(sc * (sdot[i] + cedot) + lb);
  }
  __syncthreads();
  if (wv == 0) {   // cluster sum -> 1/sum
    float s = 0.f;
    for (int p = lane; p < Lc; p += 64) s += sc_s[p];
    for (int off = 32; off; off >>= 1) s += __shfl_down(s, off);
    if (lane == 0) sc_red = 1.f / s;
  }
  __syncthreads();
  const float inv = sc_red;
  for (int p = t; p < Lc; p += 768) {
    const int i = order[c * NN + p];
    float ps = __expf(-(float)(i + 1) * 0.0625f);   // 1/4096^(1/3) == 1/16
    ps = fmaxf(0.5f, ps);
    out[i] = 0.5f * (sc_s[p] * inv) + 0.5f * ps;
  }
}

// ---------------------------------------------------------------------------
extern "C" void kernel_launch(void* const* d_in, const int* in_sizes, int n_in,
                              void* d_out, int out_size, void* d_ws, size_t ws_size,
                              hipStream_t stream) {
  const float* sent   = (const float*)d_in[0];
  const int*   labels = (const int*)d_in[1];
  const float* W_ih0  = (const float*)d_in[2];
  const float* W_hh0  = (const float*)d_in[3];
  const float* b_ih0  = (const float*)d_in[4];
  const float* b_hh0  = (const float*)d_in[5];
  const float* W_ih1  = (const float*)d_in[6];
  const float* W_hh1  = (const float*)d_in[7];
  const float* b_ih1  = (const float*)d_in[8];
  const float* b_hh1  = (const float*)d_in[9];
  const float* lin_v  = (const float*)d_in[10];
  const float* lin_g  = (const float*)d_in[11];
  const float* lin_b  = (const float*)d_in[12];
  float* out = (float*)d_out;

  char* ws = (char*)d_ws;
  size_t off = 0;
  auto alloc = [&](size_t bytes) -> void* {
    void* p = ws + off;
    off = (off + bytes + 255) & ~(size_t)255;
    return p;
  };
  int*   order  = (int*)  alloc((size_t)KK * NN * sizeof(int));
  int*   len    = (int*)  alloc(KK * sizeof(int));
  float* scale  = (float*)alloc(sizeof(float));
  _Float16* pack = (_Float16*)alloc((size_t)18432 * 8 * sizeof(_Float16));
  float* xw     = (float*)alloc((size_t)NN * G3 * sizeof(float));
  float* sdot   = (float*)alloc((size_t)NN * sizeof(float));
  (void)ws_size; (void)in_sizes; (void)n_in; (void)out_size;

  prep_k<<<dim3(337), dim3(256), 0, stream>>>(
      labels, lin_v, lin_g, W_hh0, W_ih1, W_hh1,
      sent, W_ih0, b_ih0, order, len, scale, pack, xw, sdot);
  gru_fused_k<<<dim3(KK), dim3(768), 0, stream>>>(
      xw, pack, b_hh0, b_ih0, b_ih1, b_hh1, len, order,
      sdot, lin_v, scale, lin_b, out);
}